// Round 16
// baseline (692.165 us; speedup 1.0000x reference)
//
#include <hip/hip_runtime.h>
#include <math.h>

#define TWO_PI 6.283185307179586f

// HARNESS MODEL (verified R8-R15): d_out = 33,362,176 f32 = Re(out), [bc][l][m].
// Math: xr[c][k][m] = (2pi/720) * sum_n x[c][k][n] * cos(2pi n m/720)
//       out[c][l][m] = sum_k xr[c][k][m] * W[m][l][k]
// R16: cosine fold  y[n] = x[n] + x[720-n] (n=1..359; y0=x0, y360=x360)
//   => s1 K: 736 -> 368 (12 iters, half the MFLOPs & latency round-trips).
// MFMA product-reordering (products outer, accs inner) to break 3-long
// dependent MFMA chains (R14/R15: MfmaUtil pinned at 18% across schedules).

typedef __attribute__((ext_vector_type(8))) short bf16x8;
typedef __attribute__((ext_vector_type(4))) float f32x4;

__device__ inline unsigned short f2bf(float f) {
    union { float f; unsigned int u; } v; v.f = f;
    unsigned int u = v.u;
    return (unsigned short)((u + 0x7fffu + ((u >> 16) & 1u)) >> 16);  // RNE
}
__device__ inline float bf2f(unsigned short h) {
    union { unsigned int u; float f; } v; v.u = ((unsigned int)h) << 16;
    return v.f;
}
__device__ inline unsigned int packhl(float v) {
    unsigned short h = f2bf(v);
    unsigned short l = f2bf(v - bf2f(h));
    return (unsigned int)h | ((unsigned int)l << 16);
}
__device__ inline void split2(float a, float b, unsigned int& hh, unsigned int& ll) {
    unsigned short ha = f2bf(a), hb = f2bf(b);
    unsigned short la = f2bf(a - bf2f(ha)), lb = f2bf(b - bf2f(hb));
    hh = (unsigned int)ha | ((unsigned int)hb << 16);
    ll = (unsigned int)la | ((unsigned int)lb << 16);
}
// truncation split: v = hi + (v-hi) with exact residual capture (~2^-16 rel)
__device__ inline void split2t(float a, float b, unsigned int& hh, unsigned int& ll) {
    union { float f; unsigned int u; } ua, ub, fa, fb, la, lb;
    ua.f = a; ub.f = b;
    hh = (ua.u >> 16) | (ub.u & 0xffff0000u);
    fa.u = ua.u & 0xffff0000u;
    fb.u = ub.u & 0xffff0000u;
    la.f = a - fa.f;
    lb.f = b - fb.f;
    ll = (la.u >> 16) | (lb.u & 0xffff0000u);
}
// bijective chunked XCD swizzle (m204)
__device__ inline int xcd_work(int bid, int nwg) {
    int q = nwg >> 3, r = nwg & 7;
    int xcd = bid & 7, ord = bid >> 3;
    return (xcd < r ? xcd * (q + 1) : r * (q + 1) + (xcd - r) * q) + ord;
}

// ---------------- tables: EcT_hi/lo [384][384] bf16, EcT[m][n] = sigma*cos, n<=360 ----------------
__global__ void build_ect(unsigned short* __restrict__ Eh,
                          unsigned short* __restrict__ El) {
    const float sigma = TWO_PI / 720.0f;
    const int total = 384 * 384;
    for (int i = blockIdx.x * blockDim.x + threadIdx.x; i < total;
         i += gridDim.x * blockDim.x) {
        int m = i / 384, n = i % 384;
        float v = 0.f;
        if (m < 361 && n <= 360) {
            int r = (n * m) % 720;  // exact phase reduction
            v = sigma * cosf((float)r * (TWO_PI / 720.0f));
        }
        unsigned short h = f2bf(v);
        Eh[i] = h;
        El[i] = f2bf(v - bf2f(h));
    }
}

// ---------------- stage 1: xr[m][q] = sum_{n<=360} y[q][n]*EcT[m][n] ----------------
// 256 thr = 4 waves; tile 64q x 96m; K=368 padded (12 iters); dbuf, 1 barrier/iter
__global__ __launch_bounds__(256, 4) void s1_mfma(
    const float* __restrict__ x, const unsigned short* __restrict__ Eh,
    const unsigned short* __restrict__ El, unsigned int* __restrict__ xrp,
    const int Q) {
    __shared__ short Ah[2][4][64][8], Al[2][4][64][8];   // 16 KB
    __shared__ short Bt[2][2][4][96][8];                 // 24.5 KB -> 40 KB total

    const int work = xcd_work(blockIdx.x, gridDim.x);
    const int q0 = (work >> 2) * 64;
    const int m0g = (work & 3) * 96;
    const int t = threadIdx.x;
    const int lane = t & 63, wv = t >> 6;
    const int lr = lane & 15, lk = lane >> 4;
    const int wq = wv;

    const int ar = t >> 2, akc = t & 3;
    const int aq = q0 + ar;
    const float* arow = x + (size_t)aq * 720;
    const bool aqv = (aq < Q);

    const unsigned short* btp[3];
    int bgo[3], bco[3];
#pragma unroll
    for (int i = 0; i < 3; ++i) {
        int id = t + i * 256;
        int tab = id / 384, rem = id % 384;
        int kc = rem / 96, r = rem % 96;
        btp[i] = tab ? El : Eh;
        bgo[i] = (m0g + r) * 384 + kc * 8;
        bco[i] = ((tab * 4 + kc) * 96 + r) * 16;
    }

    f32x4 acc[6];
#pragma unroll
    for (int nj = 0; nj < 6; ++nj)
#pragma unroll
        for (int r = 0; r < 4; ++r) acc[nj][r] = 0.f;

    float4 f0a, f0b, pra, prb;   // raw prefetch; fold+split happen in WRITEA

    // y[n] = x[n]+x[720-n] (1<=n<=359), y[0]=x[0], y[360]=x[360], else 0.
    // pair[j] (j=0..7, n=kg+j) = addr[7-j] where addr[i] = x[713-kg+i].
#define S1_LOADA(K0)                                                       \
    {                                                                      \
        int kg = (K0) + akc * 8;                                           \
        f0a = make_float4(0.f, 0.f, 0.f, 0.f);                             \
        f0b = f0a; pra = f0a; prb = f0a;                                   \
        if (aqv) {                                                         \
            if (kg <= 352) {                                               \
                f0a = *(const float4*)(arow + kg);                         \
                f0b = *(const float4*)(arow + kg + 4);                     \
            } else if (kg == 360) {                                        \
                f0a.x = arow[360];                                         \
            }                                                              \
            if (kg >= 8 && kg <= 352) {                                    \
                pra = *(const float4*)(arow + 713 - kg);                   \
                prb = *(const float4*)(arow + 717 - kg);                   \
            } else if (kg == 0) {                                          \
                float tm[8];                                               \
                _Pragma("unroll") for (int i = 0; i < 8; ++i) {            \
                    int n = 7 - i;                                         \
                    tm[i] = (n >= 1) ? arow[713 + i] : 0.f;                \
                }                                                          \
                pra = make_float4(tm[0], tm[1], tm[2], tm[3]);             \
                prb = make_float4(tm[4], tm[5], tm[6], tm[7]);             \
            }                                                              \
        }                                                                  \
    }
#define S1_WRITEA(NB)                                                     \
    {                                                                     \
        float y0 = f0a.x + prb.w, y1 = f0a.y + prb.z;                     \
        float y2 = f0a.z + prb.y, y3 = f0a.w + prb.x;                     \
        float y4 = f0b.x + pra.w, y5 = f0b.y + pra.z;                     \
        float y6 = f0b.z + pra.y, y7 = f0b.w + pra.x;                     \
        unsigned int h0, h1, h2, h3, l0, l1, l2, l3;                      \
        split2t(y0, y1, h0, l0);                                          \
        split2t(y2, y3, h1, l1);                                          \
        split2t(y4, y5, h2, l2);                                          \
        split2t(y6, y7, h3, l3);                                          \
        *(uint4*)&Ah[NB][akc][ar][0] = make_uint4(h0, h1, h2, h3);        \
        *(uint4*)&Al[NB][akc][ar][0] = make_uint4(l0, l1, l2, l3);        \
    }
#define S1_COPYB(NB, K0)                                                  \
    {                                                                     \
        char* bb = (char*)&Bt[NB][0][0][0][0];                            \
        _Pragma("unroll") for (int i = 0; i < 3; ++i) {                   \
            uint4 v = *(const uint4*)(btp[i] + bgo[i] + (K0));            \
            *(uint4*)(bb + bco[i]) = v;                                   \
        }                                                                 \
    }

    S1_LOADA(0);
    S1_WRITEA(0);
    S1_COPYB(0, 0);
    __syncthreads();
    int cur = 0;
    const int NIT = 12;   // K = 368 padded to 384
    for (int it = 0; it < NIT; ++it) {
        const int nb = cur ^ 1;
        if (it + 1 < NIT) S1_LOADA((it + 1) * 32);
        bf16x8 ah = *(const bf16x8*)&Ah[cur][lk][wq * 16 + lr][0];
        bf16x8 al = *(const bf16x8*)&Al[cur][lk][wq * 16 + lr][0];
        // products outer: 6 independent MFMAs between dependent pairs
#pragma unroll
        for (int nj = 0; nj < 6; ++nj) {
            bf16x8 bh = *(const bf16x8*)&Bt[cur][0][lk][nj * 16 + lr][0];
            acc[nj] = __builtin_amdgcn_mfma_f32_16x16x32_bf16(ah, bh, acc[nj], 0, 0, 0);
        }
#pragma unroll
        for (int nj = 0; nj < 6; ++nj) {
            bf16x8 bl = *(const bf16x8*)&Bt[cur][1][lk][nj * 16 + lr][0];
            acc[nj] = __builtin_amdgcn_mfma_f32_16x16x32_bf16(ah, bl, acc[nj], 0, 0, 0);
        }
#pragma unroll
        for (int nj = 0; nj < 6; ++nj) {
            bf16x8 bh = *(const bf16x8*)&Bt[cur][0][lk][nj * 16 + lr][0];
            acc[nj] = __builtin_amdgcn_mfma_f32_16x16x32_bf16(al, bh, acc[nj], 0, 0, 0);
        }
        if (it + 1 < NIT) {
            S1_WRITEA(nb);
            S1_COPYB(nb, (it + 1) * 32);
            __syncthreads();
            cur = nb;
        }
    }

    // epilogue: D col=m, row=q (verified mapping)
#pragma unroll
    for (int nj = 0; nj < 6; ++nj) {
        int m = m0g + nj * 16 + lr;
        if (m >= 361) continue;
        size_t base = (size_t)m * Q;
#pragma unroll
        for (int reg = 0; reg < 4; ++reg) {
            int q = q0 + wq * 16 + lk * 4 + reg;
            if (q < Q) xrp[base + q] = packhl(acc[nj][reg]);
        }
    }
}

// ---------------- stage 2: per-m GEMM, tile 128bc x 64l, pipelined ----------------
__global__ __launch_bounds__(256, 4) void s2_mfma(
    const unsigned int* __restrict__ xrp, const float* __restrict__ W,
    float* __restrict__ stg, const int CH) {
    __shared__ short Ah[128][40], Al[128][40];   // 10 KB each
    __shared__ short Bh[64][40], Bl[64][40];     // 5 KB each -> 30 KB

    const int work = xcd_work(blockIdx.x, gridDim.x);
    const int m = work / 12;
    const int rem = work % 12;
    const int half = rem / 6, lt = rem % 6;
    const int l0 = lt * 64;
    if (l0 + 63 < m) return;          // dead tile: zero-filled by transpose
    const int bcbase = half * 128;
    if (bcbase >= CH) return;
    const int Q = CH * 361;
    const int t = threadIdx.x;
    const int lane = t & 63, wv = t >> 6;
    const int lr = lane & 15, lk = lane >> 4;
    const int wbc = wv >> 1, wl = wv & 1;

    const unsigned int* Am = xrp + (size_t)m * Q;
    const float* Wm = W + (size_t)m * 130321;

    f32x4 acc[4][2];
#pragma unroll
    for (int fi = 0; fi < 4; ++fi)
#pragma unroll
        for (int ni = 0; ni < 2; ++ni)
#pragma unroll
            for (int r = 0; r < 4; ++r) acc[fi][ni][r] = 0.f;

    unsigned int pa0[8], pa1[8];
    float wva[4], wvb[4];

#define S2_LOADR(K0)                                                          \
    {                                                                         \
        _Pragma("unroll") for (int i = 0; i < 8; ++i) {                       \
            int id = t + i * 256;                                             \
            int r = id >> 4, kp = id & 15;                                    \
            int bc = bcbase + r, kg = (K0) + kp * 2;                          \
            unsigned int p0 = 0, p1 = 0;                                      \
            if (bc < CH) {                                                    \
                size_t base = (size_t)bc * 361;                               \
                if (kg < 361) p0 = Am[base + kg];                             \
                if (kg + 1 < 361) p1 = Am[base + kg + 1];                     \
            }                                                                 \
            pa0[i] = p0; pa1[i] = p1;                                         \
        }                                                                     \
        _Pragma("unroll") for (int i = 0; i < 4; ++i) {                       \
            int id = t + i * 256;                                             \
            int r = id >> 4, kp = id & 15;                                    \
            int l = l0 + r, kg = (K0) + kp * 2;                               \
            float va = 0.f, vb = 0.f;                                         \
            if (l < 361) {                                                    \
                size_t base = (size_t)l * 361;                                \
                if (kg < 361) va = Wm[base + kg];                             \
                if (kg + 1 < 361) vb = Wm[base + kg + 1];                     \
            }                                                                 \
            wva[i] = va; wvb[i] = vb;                                         \
        }                                                                     \
    }
#define S2_WRITES()                                                           \
    {                                                                         \
        _Pragma("unroll") for (int i = 0; i < 8; ++i) {                       \
            int id = t + i * 256;                                             \
            int r = id >> 4, kp = id & 15;                                    \
            *(unsigned int*)&Ah[r][kp * 2] =                                  \
                (pa0[i] & 0xffffu) | (pa1[i] << 16);                          \
            *(unsigned int*)&Al[r][kp * 2] =                                  \
                (pa0[i] >> 16) | (pa1[i] & 0xffff0000u);                      \
        }                                                                     \
        _Pragma("unroll") for (int i = 0; i < 4; ++i) {                       \
            int id = t + i * 256;                                             \
            int r = id >> 4, kp = id & 15;                                    \
            unsigned int hh, ll;                                              \
            split2(wva[i], wvb[i], hh, ll);                                   \
            *(unsigned int*)&Bh[r][kp * 2] = hh;                              \
            *(unsigned int*)&Bl[r][kp * 2] = ll;                              \
        }                                                                     \
    }

    S2_LOADR(0);
    S2_WRITES();
    __syncthreads();
    for (int it = 0; it < 12; ++it) {
        if (it + 1 < 12) S2_LOADR((it + 1) * 32);
        // products outer: 8 independent MFMAs between dependent pairs
#pragma unroll
        for (int fi = 0; fi < 4; ++fi) {
            bf16x8 a = *(const bf16x8*)&Ah[wbc * 64 + fi * 16 + lr][lk * 8];
#pragma unroll
            for (int ni = 0; ni < 2; ++ni) {
                bf16x8 b = *(const bf16x8*)&Bh[wl * 32 + ni * 16 + lr][lk * 8];
                acc[fi][ni] = __builtin_amdgcn_mfma_f32_16x16x32_bf16(a, b, acc[fi][ni], 0, 0, 0);
            }
        }
#pragma unroll
        for (int fi = 0; fi < 4; ++fi) {
            bf16x8 a = *(const bf16x8*)&Ah[wbc * 64 + fi * 16 + lr][lk * 8];
#pragma unroll
            for (int ni = 0; ni < 2; ++ni) {
                bf16x8 b = *(const bf16x8*)&Bl[wl * 32 + ni * 16 + lr][lk * 8];
                acc[fi][ni] = __builtin_amdgcn_mfma_f32_16x16x32_bf16(a, b, acc[fi][ni], 0, 0, 0);
            }
        }
#pragma unroll
        for (int fi = 0; fi < 4; ++fi) {
            bf16x8 a = *(const bf16x8*)&Al[wbc * 64 + fi * 16 + lr][lk * 8];
#pragma unroll
            for (int ni = 0; ni < 2; ++ni) {
                bf16x8 b = *(const bf16x8*)&Bh[wl * 32 + ni * 16 + lr][lk * 8];
                acc[fi][ni] = __builtin_amdgcn_mfma_f32_16x16x32_bf16(a, b, acc[fi][ni], 0, 0, 0);
            }
        }
        __syncthreads();
        if (it + 1 < 12) {
            S2_WRITES();
            __syncthreads();
        }
    }

    // epilogue: stg[(m*CH+bc)*361+l]
#pragma unroll
    for (int fi = 0; fi < 4; ++fi) {
#pragma unroll
        for (int ni = 0; ni < 2; ++ni) {
            int l = l0 + wl * 32 + ni * 16 + lr;
#pragma unroll
            for (int reg = 0; reg < 4; ++reg) {
                int bc = bcbase + wbc * 64 + fi * 16 + lk * 4 + reg;
                if (bc < CH && l < 361)
                    stg[((size_t)m * CH + bc) * 361 + l] = acc[fi][ni][reg];
            }
        }
    }
}

// ---------------- transpose stg [m][q'] -> out, zero-filling dead tiles ----------------
__global__ __launch_bounds__(256) void transpose_out(const float* __restrict__ stg,
                                                     float* __restrict__ out,
                                                     const int c0, const int CH) {
    __shared__ float tile[32][33];
    const int Q = CH * 361;
    const int m0 = blockIdx.y * 32, q0 = blockIdx.x * 32;
    const int tx = threadIdx.x & 31, ty = threadIdx.x >> 5;
    for (int i = ty; i < 32; i += 8) {
        int mm = m0 + i, q = q0 + tx;
        float v = 0.f;
        if (mm < 361 && q < Q) {
            int l = q % 361;
            if ((l | 63) >= mm) v = stg[(size_t)mm * Q + q];  // live 64-tile
        }
        tile[i][tx] = v;
    }
    __syncthreads();
    for (int i = ty; i < 32; i += 8) {
        int q = q0 + i, mm = m0 + tx;
        if (mm < 361 && q < Q)
            out[((size_t)c0 * 361 + q) * 361 + mm] = tile[tx][i];
    }
}

extern "C" void kernel_launch(void* const* d_in, const int* in_sizes, int n_in,
                              void* d_out, int out_size, void* d_ws, size_t ws_size,
                              hipStream_t stream) {
    (void)out_size;
    // select inputs by element count: x = 66,539,520; W = 47,045,881
    const float* x = (const float*)d_in[0];
    const float* W = (const float*)d_in[1];
    if (n_in >= 2 && (in_sizes[0] == 47045881 || in_sizes[1] == 66539520)) {
        x = (const float*)d_in[1];
        W = (const float*)d_in[0];
    }
    float* out = (float*)d_out;

    // ws layout (bytes): EcT_hi [384][384] | EcT_lo | xrp (uint) | stg (f32)
    const size_t offEh = 0;
    const size_t offEl = 294912;                 // 384*384*2
    const size_t offData = 589824;

    const int cands[6] = {256, 128, 64, 32, 16, 8};
    int CH = 0;
    for (int i = 0; i < 6; ++i) {
        size_t need = offData + 2ull * cands[i] * 130321ull * 4ull;
        if (need <= ws_size) { CH = cands[i]; break; }
    }
    if (!CH) return;  // workspace too small: fail visibly, don't fault

    unsigned short* Eh = (unsigned short*)((char*)d_ws + offEh);
    unsigned short* El = (unsigned short*)((char*)d_ws + offEl);
    unsigned int* xrp = (unsigned int*)((char*)d_ws + offData);
    float* stg = (float*)((char*)d_ws + offData + (size_t)CH * 130321ull * 4ull);

    build_ect<<<256, 256, 0, stream>>>(Eh, El);

    const int Q = CH * 361;
    const int qt = (Q + 63) / 64;
    for (int c0 = 0; c0 < 256; c0 += CH) {
        s1_mfma<<<qt * 4, 256, 0, stream>>>(
            x + (size_t)c0 * 361 * 720, Eh, El, xrp, Q);
        s2_mfma<<<361 * 12, 256, 0, stream>>>(xrp, W, stg, CH);
        transpose_out<<<dim3((Q + 31) / 32, 12), 256, 0, stream>>>(stg, out, c0, CH);
    }
}

// Round 17
// 606.754 us; speedup vs baseline: 1.1408x; 1.1408x over previous
//
#include <hip/hip_runtime.h>
#include <math.h>

#define TWO_PI 6.283185307179586f

// HARNESS MODEL (verified R8-R16): d_out = 33,362,176 f32 = Re(out), [bc][l][m].
// Math: xr[c][k][m] = (2pi/720) * sum_n x[c][k][n] * cos(2pi n m/720)
//       out[c][l][m] = sum_k xr[c][k][m] * W[m][l][k]
// R17: keep R16's cosine fold (K 736->368, 12 iters); REVERT the MFMA
// product-reordering in both kernels (R16: s2 190->353us — per-MFMA LDS
// re-reads put ds_read latency on the critical path). s2 = R14's proven form.

typedef __attribute__((ext_vector_type(8))) short bf16x8;
typedef __attribute__((ext_vector_type(4))) float f32x4;

__device__ inline unsigned short f2bf(float f) {
    union { float f; unsigned int u; } v; v.f = f;
    unsigned int u = v.u;
    return (unsigned short)((u + 0x7fffu + ((u >> 16) & 1u)) >> 16);  // RNE
}
__device__ inline float bf2f(unsigned short h) {
    union { unsigned int u; float f; } v; v.u = ((unsigned int)h) << 16;
    return v.f;
}
__device__ inline unsigned int packhl(float v) {
    unsigned short h = f2bf(v);
    unsigned short l = f2bf(v - bf2f(h));
    return (unsigned int)h | ((unsigned int)l << 16);
}
__device__ inline void split2(float a, float b, unsigned int& hh, unsigned int& ll) {
    unsigned short ha = f2bf(a), hb = f2bf(b);
    unsigned short la = f2bf(a - bf2f(ha)), lb = f2bf(b - bf2f(hb));
    hh = (unsigned int)ha | ((unsigned int)hb << 16);
    ll = (unsigned int)la | ((unsigned int)lb << 16);
}
// truncation split: v = hi + (v-hi), residual exact (~2^-16 rel)
__device__ inline void split2t(float a, float b, unsigned int& hh, unsigned int& ll) {
    union { float f; unsigned int u; } ua, ub, fa, fb, la, lb;
    ua.f = a; ub.f = b;
    hh = (ua.u >> 16) | (ub.u & 0xffff0000u);
    fa.u = ua.u & 0xffff0000u;
    fb.u = ub.u & 0xffff0000u;
    la.f = a - fa.f;
    lb.f = b - fb.f;
    ll = (la.u >> 16) | (lb.u & 0xffff0000u);
}
// bijective chunked XCD swizzle (m204)
__device__ inline int xcd_work(int bid, int nwg) {
    int q = nwg >> 3, r = nwg & 7;
    int xcd = bid & 7, ord = bid >> 3;
    return (xcd < r ? xcd * (q + 1) : r * (q + 1) + (xcd - r) * q) + ord;
}

// ---------------- tables: EcT_hi/lo [384][384] bf16, EcT[m][n] = sigma*cos, n<=360 ----------------
__global__ void build_ect(unsigned short* __restrict__ Eh,
                          unsigned short* __restrict__ El) {
    const float sigma = TWO_PI / 720.0f;
    const int total = 384 * 384;
    for (int i = blockIdx.x * blockDim.x + threadIdx.x; i < total;
         i += gridDim.x * blockDim.x) {
        int m = i / 384, n = i % 384;
        float v = 0.f;
        if (m < 361 && n <= 360) {
            int r = (n * m) % 720;  // exact phase reduction
            v = sigma * cosf((float)r * (TWO_PI / 720.0f));
        }
        unsigned short h = f2bf(v);
        Eh[i] = h;
        El[i] = f2bf(v - bf2f(h));
    }
}

// ---------------- stage 1: xr[m][q] = sum_{n<=360} y[q][n]*EcT[m][n] ----------------
// y[n] = x[n]+x[720-n] (n=1..359), y0=x0, y360=x360.  12 iters, dbuf, 1 barrier.
__global__ __launch_bounds__(256, 4) void s1_mfma(
    const float* __restrict__ x, const unsigned short* __restrict__ Eh,
    const unsigned short* __restrict__ El, unsigned int* __restrict__ xrp,
    const int Q) {
    __shared__ short Ah[2][4][64][8], Al[2][4][64][8];   // 16 KB
    __shared__ short Bt[2][2][4][96][8];                 // 24.5 KB -> 40 KB total

    const int work = xcd_work(blockIdx.x, gridDim.x);
    const int q0 = (work >> 2) * 64;
    const int m0g = (work & 3) * 96;
    const int t = threadIdx.x;
    const int lane = t & 63, wv = t >> 6;
    const int lr = lane & 15, lk = lane >> 4;
    const int wq = wv;

    const int ar = t >> 2, akc = t & 3;
    const int aq = q0 + ar;
    const float* arow = x + (size_t)aq * 720;
    const bool aqv = (aq < Q);

    const unsigned short* btp[3];
    int bgo[3], bco[3];
#pragma unroll
    for (int i = 0; i < 3; ++i) {
        int id = t + i * 256;
        int tab = id / 384, rem = id % 384;
        int kc = rem / 96, r = rem % 96;
        btp[i] = tab ? El : Eh;
        bgo[i] = (m0g + r) * 384 + kc * 8;
        bco[i] = ((tab * 4 + kc) * 96 + r) * 16;
    }

    f32x4 acc[6];
#pragma unroll
    for (int nj = 0; nj < 6; ++nj)
#pragma unroll
        for (int r = 0; r < 4; ++r) acc[nj][r] = 0.f;

    float4 f0a, f0b, pra, prb;   // raw prefetch; fold+split happen in WRITEA

#define S1_LOADA(K0)                                                       \
    {                                                                      \
        int kg = (K0) + akc * 8;                                           \
        f0a = make_float4(0.f, 0.f, 0.f, 0.f);                             \
        f0b = f0a; pra = f0a; prb = f0a;                                   \
        if (aqv) {                                                         \
            if (kg <= 352) {                                               \
                f0a = *(const float4*)(arow + kg);                         \
                f0b = *(const float4*)(arow + kg + 4);                     \
            } else if (kg == 360) {                                        \
                f0a.x = arow[360];                                         \
            }                                                              \
            if (kg >= 8 && kg <= 352) {                                    \
                pra = *(const float4*)(arow + 713 - kg);                   \
                prb = *(const float4*)(arow + 717 - kg);                   \
            } else if (kg == 0) {                                          \
                float tm[8];                                               \
                _Pragma("unroll") for (int i = 0; i < 8; ++i) {            \
                    int n = 7 - i;                                         \
                    tm[i] = (n >= 1) ? arow[713 + i] : 0.f;                \
                }                                                          \
                pra = make_float4(tm[0], tm[1], tm[2], tm[3]);             \
                prb = make_float4(tm[4], tm[5], tm[6], tm[7]);             \
            }                                                              \
        }                                                                  \
    }
#define S1_WRITEA(NB)                                                     \
    {                                                                     \
        float y0 = f0a.x + prb.w, y1 = f0a.y + prb.z;                     \
        float y2 = f0a.z + prb.y, y3 = f0a.w + prb.x;                     \
        float y4 = f0b.x + pra.w, y5 = f0b.y + pra.z;                     \
        float y6 = f0b.z + pra.y, y7 = f0b.w + pra.x;                     \
        unsigned int h0, h1, h2, h3, l0, l1, l2, l3;                      \
        split2t(y0, y1, h0, l0);                                          \
        split2t(y2, y3, h1, l1);                                          \
        split2t(y4, y5, h2, l2);                                          \
        split2t(y6, y7, h3, l3);                                          \
        *(uint4*)&Ah[NB][akc][ar][0] = make_uint4(h0, h1, h2, h3);        \
        *(uint4*)&Al[NB][akc][ar][0] = make_uint4(l0, l1, l2, l3);        \
    }
#define S1_COPYB(NB, K0)                                                  \
    {                                                                     \
        char* bb = (char*)&Bt[NB][0][0][0][0];                            \
        _Pragma("unroll") for (int i = 0; i < 3; ++i) {                   \
            uint4 v = *(const uint4*)(btp[i] + bgo[i] + (K0));            \
            *(uint4*)(bb + bco[i]) = v;                                   \
        }                                                                 \
    }

    S1_LOADA(0);
    S1_WRITEA(0);
    S1_COPYB(0, 0);
    __syncthreads();
    int cur = 0;
    const int NIT = 12;   // K = 368 padded to 384
    for (int it = 0; it < NIT; ++it) {
        const int nb = cur ^ 1;
        if (it + 1 < NIT) S1_LOADA((it + 1) * 32);
        bf16x8 ah = *(const bf16x8*)&Ah[cur][lk][wq * 16 + lr][0];
        bf16x8 al = *(const bf16x8*)&Al[cur][lk][wq * 16 + lr][0];
        // R15-proven ordering: per nj load bh/bl once, 3 chained MFMAs
#pragma unroll
        for (int nj = 0; nj < 6; ++nj) {
            bf16x8 bh = *(const bf16x8*)&Bt[cur][0][lk][nj * 16 + lr][0];
            bf16x8 bl = *(const bf16x8*)&Bt[cur][1][lk][nj * 16 + lr][0];
            acc[nj] = __builtin_amdgcn_mfma_f32_16x16x32_bf16(ah, bh, acc[nj], 0, 0, 0);
            acc[nj] = __builtin_amdgcn_mfma_f32_16x16x32_bf16(ah, bl, acc[nj], 0, 0, 0);
            acc[nj] = __builtin_amdgcn_mfma_f32_16x16x32_bf16(al, bh, acc[nj], 0, 0, 0);
        }
        if (it + 1 < NIT) {
            S1_WRITEA(nb);
            S1_COPYB(nb, (it + 1) * 32);
            __syncthreads();
            cur = nb;
        }
    }

    // epilogue: D col=m, row=q (verified mapping)
#pragma unroll
    for (int nj = 0; nj < 6; ++nj) {
        int m = m0g + nj * 16 + lr;
        if (m >= 361) continue;
        size_t base = (size_t)m * Q;
#pragma unroll
        for (int reg = 0; reg < 4; ++reg) {
            int q = q0 + wq * 16 + lk * 4 + reg;
            if (q < Q) xrp[base + q] = packhl(acc[nj][reg]);
        }
    }
}

// ---------------- stage 2: per-m GEMM, tile 128bc x 64l (R14 proven form) ----------------
__global__ __launch_bounds__(256, 4) void s2_mfma(
    const unsigned int* __restrict__ xrp, const float* __restrict__ W,
    float* __restrict__ stg, const int CH) {
    __shared__ short Ah[128][40], Al[128][40];   // 10 KB each
    __shared__ short Bh[64][40], Bl[64][40];     // 5 KB each -> 30 KB

    const int work = xcd_work(blockIdx.x, gridDim.x);
    const int m = work / 12;
    const int rem = work % 12;
    const int half = rem / 6, lt = rem % 6;
    const int l0 = lt * 64;
    if (l0 + 63 < m) return;          // dead tile: zero-filled by transpose
    const int bcbase = half * 128;
    if (bcbase >= CH) return;
    const int Q = CH * 361;
    const int t = threadIdx.x;
    const int lane = t & 63, wv = t >> 6;
    const int lr = lane & 15, lk = lane >> 4;
    const int wbc = wv >> 1, wl = wv & 1;

    const unsigned int* Am = xrp + (size_t)m * Q;
    const float* Wm = W + (size_t)m * 130321;

    f32x4 acc[4][2];
#pragma unroll
    for (int fi = 0; fi < 4; ++fi)
#pragma unroll
        for (int ni = 0; ni < 2; ++ni)
#pragma unroll
            for (int r = 0; r < 4; ++r) acc[fi][ni][r] = 0.f;

    unsigned int pa0[8], pa1[8];
    float wva[4], wvb[4];

#define S2_LOADR(K0)                                                          \
    {                                                                         \
        _Pragma("unroll") for (int i = 0; i < 8; ++i) {                       \
            int id = t + i * 256;                                             \
            int r = id >> 4, kp = id & 15;                                    \
            int bc = bcbase + r, kg = (K0) + kp * 2;                          \
            unsigned int p0 = 0, p1 = 0;                                      \
            if (bc < CH) {                                                    \
                size_t base = (size_t)bc * 361;                               \
                if (kg < 361) p0 = Am[base + kg];                             \
                if (kg + 1 < 361) p1 = Am[base + kg + 1];                     \
            }                                                                 \
            pa0[i] = p0; pa1[i] = p1;                                         \
        }                                                                     \
        _Pragma("unroll") for (int i = 0; i < 4; ++i) {                       \
            int id = t + i * 256;                                             \
            int r = id >> 4, kp = id & 15;                                    \
            int l = l0 + r, kg = (K0) + kp * 2;                               \
            float va = 0.f, vb = 0.f;                                         \
            if (l < 361) {                                                    \
                size_t base = (size_t)l * 361;                                \
                if (kg < 361) va = Wm[base + kg];                             \
                if (kg + 1 < 361) vb = Wm[base + kg + 1];                     \
            }                                                                 \
            wva[i] = va; wvb[i] = vb;                                         \
        }                                                                     \
    }
#define S2_WRITES()                                                           \
    {                                                                         \
        _Pragma("unroll") for (int i = 0; i < 8; ++i) {                       \
            int id = t + i * 256;                                             \
            int r = id >> 4, kp = id & 15;                                    \
            *(unsigned int*)&Ah[r][kp * 2] =                                  \
                (pa0[i] & 0xffffu) | (pa1[i] << 16);                          \
            *(unsigned int*)&Al[r][kp * 2] =                                  \
                (pa0[i] >> 16) | (pa1[i] & 0xffff0000u);                      \
        }                                                                     \
        _Pragma("unroll") for (int i = 0; i < 4; ++i) {                       \
            int id = t + i * 256;                                             \
            int r = id >> 4, kp = id & 15;                                    \
            unsigned int hh, ll;                                              \
            split2(wva[i], wvb[i], hh, ll);                                   \
            *(unsigned int*)&Bh[r][kp * 2] = hh;                              \
            *(unsigned int*)&Bl[r][kp * 2] = ll;                              \
        }                                                                     \
    }

    S2_LOADR(0);
    S2_WRITES();
    __syncthreads();
    for (int it = 0; it < 12; ++it) {
        if (it + 1 < 12) S2_LOADR((it + 1) * 32);
#pragma unroll
        for (int fi = 0; fi < 4; ++fi) {
            bf16x8 ah = *(const bf16x8*)&Ah[wbc * 64 + fi * 16 + lr][lk * 8];
            bf16x8 al = *(const bf16x8*)&Al[wbc * 64 + fi * 16 + lr][lk * 8];
#pragma unroll
            for (int ni = 0; ni < 2; ++ni) {
                bf16x8 bh = *(const bf16x8*)&Bh[wl * 32 + ni * 16 + lr][lk * 8];
                bf16x8 bl = *(const bf16x8*)&Bl[wl * 32 + ni * 16 + lr][lk * 8];
                acc[fi][ni] = __builtin_amdgcn_mfma_f32_16x16x32_bf16(ah, bh, acc[fi][ni], 0, 0, 0);
                acc[fi][ni] = __builtin_amdgcn_mfma_f32_16x16x32_bf16(ah, bl, acc[fi][ni], 0, 0, 0);
                acc[fi][ni] = __builtin_amdgcn_mfma_f32_16x16x32_bf16(al, bh, acc[fi][ni], 0, 0, 0);
            }
        }
        __syncthreads();
        if (it + 1 < 12) {
            S2_WRITES();
            __syncthreads();
        }
    }

    // epilogue: stg[(m*CH+bc)*361+l]
#pragma unroll
    for (int fi = 0; fi < 4; ++fi) {
#pragma unroll
        for (int ni = 0; ni < 2; ++ni) {
            int l = l0 + wl * 32 + ni * 16 + lr;
#pragma unroll
            for (int reg = 0; reg < 4; ++reg) {
                int bc = bcbase + wbc * 64 + fi * 16 + lk * 4 + reg;
                if (bc < CH && l < 361)
                    stg[((size_t)m * CH + bc) * 361 + l] = acc[fi][ni][reg];
            }
        }
    }
}

// ---------------- transpose stg [m][q'] -> out, zero-filling dead tiles ----------------
__global__ __launch_bounds__(256) void transpose_out(const float* __restrict__ stg,
                                                     float* __restrict__ out,
                                                     const int c0, const int CH) {
    __shared__ float tile[32][33];
    const int Q = CH * 361;
    const int m0 = blockIdx.y * 32, q0 = blockIdx.x * 32;
    const int tx = threadIdx.x & 31, ty = threadIdx.x >> 5;
    for (int i = ty; i < 32; i += 8) {
        int mm = m0 + i, q = q0 + tx;
        float v = 0.f;
        if (mm < 361 && q < Q) {
            int l = q % 361;
            if ((l | 63) >= mm) v = stg[(size_t)mm * Q + q];  // live 64-tile
        }
        tile[i][tx] = v;
    }
    __syncthreads();
    for (int i = ty; i < 32; i += 8) {
        int q = q0 + i, mm = m0 + tx;
        if (mm < 361 && q < Q)
            out[((size_t)c0 * 361 + q) * 361 + mm] = tile[tx][i];
    }
}

extern "C" void kernel_launch(void* const* d_in, const int* in_sizes, int n_in,
                              void* d_out, int out_size, void* d_ws, size_t ws_size,
                              hipStream_t stream) {
    (void)out_size;
    // select inputs by element count: x = 66,539,520; W = 47,045,881
    const float* x = (const float*)d_in[0];
    const float* W = (const float*)d_in[1];
    if (n_in >= 2 && (in_sizes[0] == 47045881 || in_sizes[1] == 66539520)) {
        x = (const float*)d_in[1];
        W = (const float*)d_in[0];
    }
    float* out = (float*)d_out;

    // ws layout (bytes): EcT_hi [384][384] | EcT_lo | xrp (uint) | stg (f32)
    const size_t offEh = 0;
    const size_t offEl = 294912;                 // 384*384*2
    const size_t offData = 589824;

    const int cands[6] = {256, 128, 64, 32, 16, 8};
    int CH = 0;
    for (int i = 0; i < 6; ++i) {
        size_t need = offData + 2ull * cands[i] * 130321ull * 4ull;
        if (need <= ws_size) { CH = cands[i]; break; }
    }
    if (!CH) return;  // workspace too small: fail visibly, don't fault

    unsigned short* Eh = (unsigned short*)((char*)d_ws + offEh);
    unsigned short* El = (unsigned short*)((char*)d_ws + offEl);
    unsigned int* xrp = (unsigned int*)((char*)d_ws + offData);
    float* stg = (float*)((char*)d_ws + offData + (size_t)CH * 130321ull * 4ull);

    build_ect<<<256, 256, 0, stream>>>(Eh, El);

    const int Q = CH * 361;
    const int qt = (Q + 63) / 64;
    for (int c0 = 0; c0 < 256; c0 += CH) {
        s1_mfma<<<qt * 4, 256, 0, stream>>>(
            x + (size_t)c0 * 361 * 720, Eh, El, xrp, Q);
        s2_mfma<<<361 * 12, 256, 0, stream>>>(xrp, W, stg, CH);
        transpose_out<<<dim3((Q + 31) / 32, 12), 256, 0, stream>>>(stg, out, c0, CH);
    }
}